// Round 9
// baseline (1421.795 us; speedup 1.0000x reference)
//
#include <hip/hip_runtime.h>
#include <hip/hip_bf16.h>
#include <hip/hip_fp16.h>

#define N_NODES 50000
#define N_EDGES 800000
#define NNIN    128
#define NOPEN   64
#define NUM_OUT 40
#define NLAYER  8
#define H2      0.01f

#define SCAN_BLOCKS ((N_NODES + 255) / 256)   // 196
#define NBKT ((N_NODES + 63) >> 6)            // 782 buckets (node>>6)
#define BCAP 4096                             // >= 45 sigma above mean 2048

// tanh(x) = 1 - 2/(exp(2x)+1); |rel err| ~1e-6.
__device__ __forceinline__ float ftanh(float x) {
    float e2 = __expf(2.0f * x);
    return 1.0f - 2.0f * __builtin_amdgcn_rcpf(e2 + 1.0f);
}

// ---- prep: degree for GCN norm (J-based + self-loop) -------------------

__global__ void deg_init(int* __restrict__ degi, int* __restrict__ deg2) {
    int n = blockIdx.x * 256 + threadIdx.x;
    if (n < N_NODES) { degi[n] = 1; deg2[n] = 0; }
}

__global__ void deg_count(const int* __restrict__ I, const int* __restrict__ J,
                          int* __restrict__ degi, int* __restrict__ deg2) {
    int e = blockIdx.x * 256 + threadIdx.x;
    if (e < N_EDGES) {
        atomicAdd(&degi[J[e]], 1);      // norm degree (reference: segment_sum over J2)
        atomicAdd(&deg2[I[e]], 1);      // structural degree, both directions
        atomicAdd(&deg2[J[e]], 1);
    }
}

__global__ void calc_dinv(const int* __restrict__ degi, float* __restrict__ dinv) {
    int n = blockIdx.x * 256 + threadIdx.x;
    if (n < N_NODES) dinv[n] = rsqrtf((float)degi[n]);
}

// ---- hierarchical exclusive scan of PADDED deg2 -> row_start -----------
// rows padded to multiples of 4 so gather's int4 entry loads are aligned.

__global__ __launch_bounds__(256) void scan1(const int* __restrict__ deg2,
                                             int* __restrict__ row_start,
                                             int* __restrict__ block_sums) {
    __shared__ int sh[256];
    int t = threadIdx.x, n = blockIdx.x * 256 + t;
    int v = (n < N_NODES) ? ((deg2[n] + 3) & ~3) : 0;
    sh[t] = v;
    __syncthreads();
#pragma unroll
    for (int off = 1; off < 256; off <<= 1) {
        int x = (t >= off) ? sh[t - off] : 0;
        __syncthreads();
        sh[t] += x;
        __syncthreads();
    }
    if (n < N_NODES) row_start[n] = sh[t] - v;  // exclusive
    if (t == 255) block_sums[blockIdx.x] = sh[t];
}

__global__ __launch_bounds__(256) void scan2(int* __restrict__ block_sums,
                                             int* __restrict__ block_off) {
    __shared__ int sh[256];
    int t = threadIdx.x;
    int v = (t < SCAN_BLOCKS) ? block_sums[t] : 0;
    sh[t] = v;
    __syncthreads();
#pragma unroll
    for (int off = 1; off < 256; off <<= 1) {
        int x = (t >= off) ? sh[t - off] : 0;
        __syncthreads();
        sh[t] += x;
        __syncthreads();
    }
    if (t < SCAN_BLOCKS) block_off[t] = sh[t] - v;  // exclusive
}

__global__ __launch_bounds__(256) void scan3(int* __restrict__ row_start,
                                             const int* __restrict__ block_off) {
    int t = threadIdx.x, n = blockIdx.x * 256 + t;
    if (n < N_NODES) row_start[n] += block_off[blockIdx.x];
}

// ---- bucketed CSR build ------------------------------------------------
// bcnt[b] = sum of deg2 over the bucket's 64 nodes (free from deg_count)

__global__ void bucket_count(const int* __restrict__ deg2, int* __restrict__ bcnt) {
    int b = blockIdx.x * 256 + threadIdx.x;
    if (b < NBKT) {
        int base = b << 6;
        int lim = min(64, N_NODES - base);
        int s = 0;
        for (int i = 0; i < lim; i++) s += deg2[base + i];
        bcnt[b] = s;
    }
}

// single-block exclusive scan over NBKT buckets; writes bk_start[NBKT+1] and bcur
__global__ __launch_bounds__(256) void bucket_scan(const int* __restrict__ bcnt,
                                                   int* __restrict__ bk_start,
                                                   int* __restrict__ bcur) {
    __shared__ int sh[256];
    __shared__ int carry;
    int t = threadIdx.x;
    if (t == 0) carry = 0;
    __syncthreads();
    for (int c0 = 0; c0 < NBKT; c0 += 256) {
        int idx = c0 + t;
        int v = (idx < NBKT) ? bcnt[idx] : 0;
        sh[t] = v;
        __syncthreads();
        for (int off = 1; off < 256; off <<= 1) {
            int x = (t >= off) ? sh[t - off] : 0;
            __syncthreads();
            sh[t] += x;
            __syncthreads();
        }
        int excl = sh[t] - v + carry;
        if (idx < NBKT) { bk_start[idx] = excl; bcur[idx] = excl; }
        __syncthreads();
        if (t == 255) carry += sh[255];
        __syncthreads();
    }
    if (t == 0) bk_start[NBKT] = carry;   // total incidences (= 2*N_EDGES)
}

// Phase A: scatter packed (n<<16)|other into per-bucket regions (L2-hot)
__global__ void fill_bucket(const int* __restrict__ I, const int* __restrict__ J,
                            int* __restrict__ bcur, unsigned* __restrict__ ebuf) {
    int e = blockIdx.x * 256 + threadIdx.x;
    if (e >= N_EDGES) return;
    int i = I[e], j = J[e];
    int p1 = atomicAdd(&bcur[i >> 6], 1);
    ebuf[p1] = ((unsigned)i << 16) | (unsigned)j;
    int p2 = atomicAdd(&bcur[j >> 6], 1);
    ebuf[p2] = ((unsigned)j << 16) | (unsigned)i;
}

// Phase B: per-bucket LDS counting sort -> final CSR ent (dense writes)
__global__ __launch_bounds__(256) void bucket_to_csr(const unsigned* __restrict__ ebuf,
                                                     const int* __restrict__ bk_start,
                                                     const int* __restrict__ row_start,
                                                     int* __restrict__ ent) {
    __shared__ unsigned eb[BCAP];
    __shared__ int cur[64];
    int b = blockIdx.x, t = threadIdx.x;
    int s = bk_start[b];
    int cnt = bk_start[b + 1] - s;
    if (cnt > BCAP) cnt = BCAP;   // statistically unreachable (45 sigma)
    for (int i = t; i < cnt; i += 256) eb[i] = ebuf[s + i];
    if (t < 64) {
        int n = (b << 6) + t;
        cur[t] = (n < N_NODES) ? row_start[n] : 0;
    }
    __syncthreads();
    for (int i = t; i < cnt; i += 256) {
        unsigned v = eb[i];
        int ln = (int)(v >> 16) & 63;
        int p = atomicAdd(&cur[ln], 1);
        ent[p] = (int)(v & 0xffffu);
    }
}

// ---- first layer: x = relu(K1 @ xn_in), xn_in is (128, N) f32 ----------
// out layout node-major: x[n*64 + o]
__global__ __launch_bounds__(256) void first_layer(const float* __restrict__ xn,
                                                   const float* __restrict__ k1f,
                                                   float* __restrict__ x_cur,
                                                   float* __restrict__ x_old) {
    __shared__ float Ks[NOPEN * 129];
    __shared__ float xs[32 * 64];
    int t = threadIdx.x;
    int n0 = blockIdx.x * 64;
    for (int idx = t; idx < NOPEN * NNIN; idx += 256)
        Ks[(idx >> 7) * 129 + (idx & 127)] = k1f[idx];

    int tn = t & 15, to = t >> 4;
    float acc[4][4] = {};
    for (int c0 = 0; c0 < NNIN; c0 += 32) {
        __syncthreads();
        for (int idx = t; idx < 32 * 64; idx += 256) {
            int ci = idx >> 6, n = idx & 63;
            int gn = n0 + n;
            xs[ci * 64 + n] = (gn < N_NODES) ? xn[(size_t)(c0 + ci) * N_NODES + gn] : 0.f;
        }
        __syncthreads();
        for (int ci = 0; ci < 32; ci++) {
            float xv[4], kv[4];
#pragma unroll
            for (int i2 = 0; i2 < 4; i2++) xv[i2] = xs[ci * 64 + tn * 4 + i2];
#pragma unroll
            for (int j = 0; j < 4; j++) kv[j] = Ks[(to * 4 + j) * 129 + c0 + ci];
#pragma unroll
            for (int i2 = 0; i2 < 4; i2++)
#pragma unroll
                for (int j = 0; j < 4; j++) acc[i2][j] += xv[i2] * kv[j];
        }
    }
#pragma unroll
    for (int i2 = 0; i2 < 4; i2++) {
        int node = n0 + tn * 4 + i2;
        if (node < N_NODES) {
            float4 st;
            st.x = fmaxf(acc[i2][0], 0.f);
            st.y = fmaxf(acc[i2][1], 0.f);
            st.z = fmaxf(acc[i2][2], 0.f);
            st.w = fmaxf(acc[i2][3], 0.f);
            *(float4*)&x_cur[(size_t)node * 64 + to * 4] = st;
            *(float4*)&x_old[(size_t)node * 64 + to * 4] = st;
        }
    }
}

// ---- Y[n][o] = sum_c K[o][c] * x[n][c], output fp16 --------------------
__global__ __launch_bounds__(256) void mat_y(const float* __restrict__ x,
                                             const float* __restrict__ K,
                                             __half* __restrict__ Y) {
    __shared__ float Ks[64 * 65];
    __shared__ float xs[64 * 65];
    int t = threadIdx.x, n0 = blockIdx.x * 64;
    for (int idx = t; idx < 4096; idx += 256) {
        int r = idx >> 6, c = idx & 63;
        Ks[r * 65 + c] = K[idx];
        int gn = n0 + r;
        xs[r * 65 + c] = (gn < N_NODES) ? x[(size_t)gn * 64 + c] : 0.f;
    }
    __syncthreads();
    int tn = t & 15, to = t >> 4;
    float acc[4][4] = {};
    for (int c = 0; c < 64; c++) {
        float xv[4], kv[4];
#pragma unroll
        for (int i2 = 0; i2 < 4; i2++) xv[i2] = xs[(tn * 4 + i2) * 65 + c];
#pragma unroll
        for (int j = 0; j < 4; j++) kv[j] = Ks[(to * 4 + j) * 65 + c];
#pragma unroll
        for (int i2 = 0; i2 < 4; i2++)
#pragma unroll
            for (int j = 0; j < 4; j++) acc[i2][j] += xv[i2] * kv[j];
    }
#pragma unroll
    for (int i2 = 0; i2 < 4; i2++) {
        int node = n0 + tn * 4 + i2;
        if (node < N_NODES) {
            __half2 h0 = __floats2half2_rn(acc[i2][0], acc[i2][1]);
            __half2 h1 = __floats2half2_rn(acc[i2][2], acc[i2][3]);
            __half2* dst = (__half2*)&Y[(size_t)node * 64 + to * 4];
            dst[0] = h0;
            dst[1] = h1;
        }
    }
}

// ---- fused gather + update: 16 waves/block, 1 wave per node ------------
// Inner loop identical to R8 (scalarized walk, w recomputed from dinv).
__global__ __launch_bounds__(1024) void gather_update(const __half* __restrict__ Y,
                                                      const float* __restrict__ x_cur,
                                                      const float* __restrict__ x_old,
                                                      const int* __restrict__ ent,
                                                      const int* __restrict__ row_start,
                                                      const int* __restrict__ deg2,
                                                      const float* __restrict__ dinv,
                                                      const float* __restrict__ K,
                                                      float* __restrict__ x_out) {
    __shared__ float Ks[64 * 65];   // K[c][o] at Ks[c*65+o]
    __shared__ float Ss[16][64];
    int t = threadIdx.x;
    for (int idx = t; idx < 4096; idx += 1024)
        Ks[(idx >> 6) * 65 + (idx & 63)] = K[idx];

    int wv = t >> 6, lane = t & 63;
    int n = blockIdx.x * 16 + wv;
    float s = 0.f;
    if (n < N_NODES) {
        float yn = __half2float(Y[(size_t)n * 64 + lane]);
        float vn = dinv[n];
        int beg = __builtin_amdgcn_readfirstlane(row_start[n]);  // % 4 == 0
        int d   = __builtin_amdgcn_readfirstlane(deg2[n]);
        int end = beg + d;
        int k = beg;
        for (; k + 3 < end; k += 4) {
            int4 oo = *(const int4*)&ent[k];               // 16B-aligned, uniform
            int o0 = __builtin_amdgcn_readfirstlane(oo.x);
            int o1 = __builtin_amdgcn_readfirstlane(oo.y);
            int o2 = __builtin_amdgcn_readfirstlane(oo.z);
            int o3 = __builtin_amdgcn_readfirstlane(oo.w);
            float y0 = __half2float(Y[((size_t)o0 << 6) + lane]);
            float y1 = __half2float(Y[((size_t)o1 << 6) + lane]);
            float y2 = __half2float(Y[((size_t)o2 << 6) + lane]);
            float y3 = __half2float(Y[((size_t)o3 << 6) + lane]);
            float w0 = dinv[o0] * vn;
            float w1 = dinv[o1] * vn;
            float w2 = dinv[o2] * vn;
            float w3 = dinv[o3] * vn;
            s += w0 * ftanh(w0 * (yn - y0));
            s += w1 * ftanh(w1 * (yn - y1));
            s += w2 * ftanh(w2 * (yn - y2));
            s += w3 * ftanh(w3 * (yn - y3));
        }
        for (; k < end; k++) {
            int o0 = __builtin_amdgcn_readfirstlane(ent[k]);
            float w0 = dinv[o0] * vn;
            float y0 = __half2float(Y[((size_t)o0 << 6) + lane]);
            s += w0 * ftanh(w0 * (yn - y0));
        }
    }
    Ss[wv][lane] = s;
    __syncthreads();
    if (n < N_NODES) {
        float acc = 0.f;
#pragma unroll 8
        for (int o = 0; o < 64; o++)
            acc += Ks[lane * 65 + o] * Ss[wv][o];   // 2-way bank alias (free) + broadcast
        float xc = x_cur[(size_t)n * 64 + lane];
        float xo = x_old[(size_t)n * 64 + lane];
        x_out[(size_t)n * 64 + lane] = 2.f * xc - xo - H2 * acc;
    }
}

// ---- out[n][o] = sum_c KNc[o][c] * x[n][c]; out is (N,40) f32 ----------
__global__ __launch_bounds__(256) void out_kernel(const float* __restrict__ x,
                                                  const float* __restrict__ Kc,
                                                  float* __restrict__ out) {
    __shared__ float xs[64 * 65];
    __shared__ float Ks[40 * 65];
    int t = threadIdx.x, n0 = blockIdx.x * 64;
    for (int idx = t; idx < 4096; idx += 256) {
        int r = idx >> 6, c = idx & 63;
        int gn = n0 + r;
        xs[r * 65 + c] = (gn < N_NODES) ? x[(size_t)gn * 64 + c] : 0.f;
    }
    for (int idx = t; idx < NUM_OUT * 64; idx += 256) {
        int r = idx >> 6, c = idx & 63;
        Ks[r * 65 + c] = Kc[idx];
    }
    __syncthreads();
    if (t < 160) {
        int tn = t & 15, to = t >> 4;
        float acc[4][4] = {};
        for (int c = 0; c < 64; c++) {
            float xv[4], kv[4];
#pragma unroll
            for (int i2 = 0; i2 < 4; i2++) xv[i2] = xs[(tn * 4 + i2) * 65 + c];
#pragma unroll
            for (int j = 0; j < 4; j++) kv[j] = Ks[(to * 4 + j) * 65 + c];
#pragma unroll
            for (int i2 = 0; i2 < 4; i2++)
#pragma unroll
                for (int j = 0; j < 4; j++) acc[i2][j] += xv[i2] * kv[j];
        }
#pragma unroll
        for (int i2 = 0; i2 < 4; i2++) {
            int node = n0 + tn * 4 + i2;
            if (node < N_NODES) {
#pragma unroll
                for (int j = 0; j < 4; j++)
                    out[(size_t)node * NUM_OUT + to * 4 + j] = acc[i2][j];
            }
        }
    }
}

extern "C" void kernel_launch(void* const* d_in, const int* in_sizes, int n_in,
                              void* d_out, int out_size, void* d_ws, size_t ws_size,
                              hipStream_t stream) {
    const float* xn = (const float*)d_in[0];
    const int*   I  = (const int*)d_in[1];
    const int*   J  = (const int*)d_in[2];
    const float* K1 = (const float*)d_in[4];
    const float* K2 = (const float*)d_in[5];
    const float* Kc = (const float*)d_in[6];

    const size_t NC = (size_t)N_NODES * NOPEN;  // 3.2M
    float*    f       = (float*)d_ws;
    float*    x_cur   = f;
    float*    x_old   = f + NC;
    __half*   Y       = (__half*)(f + 2 * NC);     // 6.4 MB
    float*    dinv    = f + 2 * NC + NC / 2;
    int*      degi    = (int*)(dinv + N_NODES);
    int*      deg2    = degi + N_NODES;
    int*      row_st  = deg2 + N_NODES;
    int*      bsums   = row_st + N_NODES;
    int*      boff    = bsums + 256;
    int*      bcnt    = boff + 256;
    int*      bk_st   = bcnt + NBKT;               // NBKT+1
    int*      bcur    = bk_st + NBKT + 1;
    unsigned* ebuf    = (unsigned*)(bcur + NBKT);  // 1.6M u32 = 6.4 MB
    int*      ent     = (int*)(ebuf + 2 * (size_t)N_EDGES);  // <= 2E+4N ints

    dim3 B(256);
    const int GN = (N_NODES + 255) / 256;   // 196
    const int GE = (N_EDGES + 255) / 256;

    deg_init<<<GN, B, 0, stream>>>(degi, deg2);
    deg_count<<<GE, B, 0, stream>>>(I, J, degi, deg2);
    calc_dinv<<<GN, B, 0, stream>>>(degi, dinv);
    scan1<<<SCAN_BLOCKS, B, 0, stream>>>(deg2, row_st, bsums);
    scan2<<<1, B, 0, stream>>>(bsums, boff);
    scan3<<<SCAN_BLOCKS, B, 0, stream>>>(row_st, boff);
    bucket_count<<<(NBKT + 255) / 256, B, 0, stream>>>(deg2, bcnt);
    bucket_scan<<<1, B, 0, stream>>>(bcnt, bk_st, bcur);
    fill_bucket<<<GE, B, 0, stream>>>(I, J, bcur, ebuf);
    bucket_to_csr<<<NBKT, B, 0, stream>>>(ebuf, bk_st, row_st, ent);

    const int NB = (N_NODES + 63) / 64;     // 782
    first_layer<<<NB, B, 0, stream>>>(xn, K1, x_cur, x_old);

    float* xc = x_cur;
    float* xo = x_old;
    for (int l = 0; l < NLAYER; l++) {
        mat_y<<<NB, B, 0, stream>>>(xc, K2 + l * NOPEN * NOPEN, Y);
        gather_update<<<(N_NODES + 15) / 16, dim3(1024), 0, stream>>>(
            Y, xc, xo, ent, row_st, deg2, dinv, K2 + l * NOPEN * NOPEN, xo);
        float* tmp = xc; xc = xo; xo = tmp;
    }
    out_kernel<<<NB, B, 0, stream>>>(xc, Kc, (float*)d_out);
}

// Round 10
// 1106.128 us; speedup vs baseline: 1.2854x; 1.2854x over previous
//
#include <hip/hip_runtime.h>
#include <hip/hip_bf16.h>
#include <hip/hip_fp16.h>

#define N_NODES 50000
#define N_EDGES 800000
#define NNIN    128
#define NOPEN   64
#define NUM_OUT 40
#define NLAYER  8
#define H2      0.01f

#define SCAN_BLOCKS ((N_NODES + 255) / 256)   // 196

// tanh(x) = 1 - 2/(exp(2x)+1); |rel err| ~1e-6.
__device__ __forceinline__ float ftanh(float x) {
    float e2 = __expf(2.0f * x);
    return 1.0f - 2.0f * __builtin_amdgcn_rcpf(e2 + 1.0f);
}

// ---- prep: degree for GCN norm (J-based + self-loop) -------------------

__global__ void deg_init(int* __restrict__ degi, int* __restrict__ deg2) {
    int n = blockIdx.x * 256 + threadIdx.x;
    if (n < N_NODES) { degi[n] = 1; deg2[n] = 0; }
}

__global__ void deg_count(const int* __restrict__ I, const int* __restrict__ J,
                          int* __restrict__ degi, int* __restrict__ deg2) {
    int e = blockIdx.x * 256 + threadIdx.x;
    if (e < N_EDGES) {
        atomicAdd(&degi[J[e]], 1);      // norm degree (reference: segment_sum over J2)
        atomicAdd(&deg2[I[e]], 1);      // structural degree, both directions
        atomicAdd(&deg2[J[e]], 1);
    }
}

__global__ void calc_dinv(const int* __restrict__ degi, float* __restrict__ dinv) {
    int n = blockIdx.x * 256 + threadIdx.x;
    if (n < N_NODES) dinv[n] = rsqrtf((float)degi[n]);
}

// ---- hierarchical exclusive scan of PADDED deg2 -> row_start -----------
// rows padded to multiples of 4 so gather's int4 entry loads are aligned.

__global__ __launch_bounds__(256) void scan1(const int* __restrict__ deg2,
                                             int* __restrict__ row_start,
                                             int* __restrict__ block_sums) {
    __shared__ int sh[256];
    int t = threadIdx.x, n = blockIdx.x * 256 + t;
    int v = (n < N_NODES) ? ((deg2[n] + 3) & ~3) : 0;
    sh[t] = v;
    __syncthreads();
#pragma unroll
    for (int off = 1; off < 256; off <<= 1) {
        int x = (t >= off) ? sh[t - off] : 0;
        __syncthreads();
        sh[t] += x;
        __syncthreads();
    }
    if (n < N_NODES) row_start[n] = sh[t] - v;  // exclusive
    if (t == 255) block_sums[blockIdx.x] = sh[t];
}

__global__ __launch_bounds__(256) void scan2(int* __restrict__ block_sums,
                                             int* __restrict__ block_off) {
    __shared__ int sh[256];
    int t = threadIdx.x;
    int v = (t < SCAN_BLOCKS) ? block_sums[t] : 0;
    sh[t] = v;
    __syncthreads();
#pragma unroll
    for (int off = 1; off < 256; off <<= 1) {
        int x = (t >= off) ? sh[t - off] : 0;
        __syncthreads();
        sh[t] += x;
        __syncthreads();
    }
    if (t < SCAN_BLOCKS) block_off[t] = sh[t] - v;  // exclusive
}

__global__ __launch_bounds__(256) void scan3(int* __restrict__ row_start,
                                             const int* __restrict__ block_off,
                                             int* __restrict__ cursor) {
    int t = threadIdx.x, n = blockIdx.x * 256 + t;
    if (n < N_NODES) {
        int r = row_start[n] + block_off[blockIdx.x];
        row_start[n] = r;
        cursor[n] = r;
    }
}

// ---- pad rows to x4 with self-index (contributes exactly 0 in gather) --
__global__ void pad_fill(const int* __restrict__ row_start,
                         const int* __restrict__ deg2,
                         int* __restrict__ ent) {
    int n = blockIdx.x * 256 + threadIdx.x;
    if (n >= N_NODES) return;
    int beg = row_start[n], d = deg2[n];
    int end4 = beg + ((d + 3) & ~3);
    for (int p = beg + d; p < end4; p++) ent[p] = n;
}

// ---- fill CSR entries: other-node index per directed incidence ---------

__global__ void fill_ent(const int* __restrict__ I, const int* __restrict__ J,
                         int* __restrict__ cursor, int* __restrict__ ent) {
    int e = blockIdx.x * 256 + threadIdx.x;
    if (e >= N_EDGES) return;
    int i = I[e], j = J[e];
    int p1 = atomicAdd(&cursor[i], 1);
    ent[p1] = j;
    int p2 = atomicAdd(&cursor[j], 1);
    ent[p2] = i;
}

// ---- first layer: x = relu(K1 @ xn_in), xn_in is (128, N) f32 ----------
// out layout node-major: x[n*64 + o]
__global__ __launch_bounds__(256) void first_layer(const float* __restrict__ xn,
                                                   const float* __restrict__ k1f,
                                                   float* __restrict__ x_cur,
                                                   float* __restrict__ x_old) {
    __shared__ float Ks[NOPEN * 129];
    __shared__ float xs[32 * 64];
    int t = threadIdx.x;
    int n0 = blockIdx.x * 64;
    for (int idx = t; idx < NOPEN * NNIN; idx += 256)
        Ks[(idx >> 7) * 129 + (idx & 127)] = k1f[idx];

    int tn = t & 15, to = t >> 4;
    float acc[4][4] = {};
    for (int c0 = 0; c0 < NNIN; c0 += 32) {
        __syncthreads();
        for (int idx = t; idx < 32 * 64; idx += 256) {
            int ci = idx >> 6, n = idx & 63;
            int gn = n0 + n;
            xs[ci * 64 + n] = (gn < N_NODES) ? xn[(size_t)(c0 + ci) * N_NODES + gn] : 0.f;
        }
        __syncthreads();
        for (int ci = 0; ci < 32; ci++) {
            float xv[4], kv[4];
#pragma unroll
            for (int i2 = 0; i2 < 4; i2++) xv[i2] = xs[ci * 64 + tn * 4 + i2];
#pragma unroll
            for (int j = 0; j < 4; j++) kv[j] = Ks[(to * 4 + j) * 129 + c0 + ci];
#pragma unroll
            for (int i2 = 0; i2 < 4; i2++)
#pragma unroll
                for (int j = 0; j < 4; j++) acc[i2][j] += xv[i2] * kv[j];
        }
    }
#pragma unroll
    for (int i2 = 0; i2 < 4; i2++) {
        int node = n0 + tn * 4 + i2;
        if (node < N_NODES) {
            float4 st;
            st.x = fmaxf(acc[i2][0], 0.f);
            st.y = fmaxf(acc[i2][1], 0.f);
            st.z = fmaxf(acc[i2][2], 0.f);
            st.w = fmaxf(acc[i2][3], 0.f);
            *(float4*)&x_cur[(size_t)node * 64 + to * 4] = st;
            *(float4*)&x_old[(size_t)node * 64 + to * 4] = st;
        }
    }
}

// ---- Y[n][o] = sum_c K[o][c] * x[n][c], output fp16 --------------------
__global__ __launch_bounds__(256) void mat_y(const float* __restrict__ x,
                                             const float* __restrict__ K,
                                             __half* __restrict__ Y) {
    __shared__ float Ks[64 * 65];
    __shared__ float xs[64 * 65];
    int t = threadIdx.x, n0 = blockIdx.x * 64;
    for (int idx = t; idx < 4096; idx += 256) {
        int r = idx >> 6, c = idx & 63;
        Ks[r * 65 + c] = K[idx];
        int gn = n0 + r;
        xs[r * 65 + c] = (gn < N_NODES) ? x[(size_t)gn * 64 + c] : 0.f;
    }
    __syncthreads();
    int tn = t & 15, to = t >> 4;
    float acc[4][4] = {};
    for (int c = 0; c < 64; c++) {
        float xv[4], kv[4];
#pragma unroll
        for (int i2 = 0; i2 < 4; i2++) xv[i2] = xs[(tn * 4 + i2) * 65 + c];
#pragma unroll
        for (int j = 0; j < 4; j++) kv[j] = Ks[(to * 4 + j) * 65 + c];
#pragma unroll
        for (int i2 = 0; i2 < 4; i2++)
#pragma unroll
            for (int j = 0; j < 4; j++) acc[i2][j] += xv[i2] * kv[j];
    }
#pragma unroll
    for (int i2 = 0; i2 < 4; i2++) {
        int node = n0 + tn * 4 + i2;
        if (node < N_NODES) {
            __half2 h0 = __floats2half2_rn(acc[i2][0], acc[i2][1]);
            __half2 h1 = __floats2half2_rn(acc[i2][2], acc[i2][3]);
            __half2* dst = (__half2*)&Y[(size_t)node * 64 + to * 4];
            dst[0] = h0;
            dst[1] = h1;
        }
    }
}

// ---- fused gather + update: 16 waves/block, 1 wave per node ------------
// Split-wave pairing: lanes 0-31 process even entries, 32-63 odd entries;
// each lane covers 2 channels via __half2 (one dword load serves 2 rows).
// Rows padded to x4 with self-index => no tail, pads contribute 0.
__global__ __launch_bounds__(1024) void gather_update(const __half* __restrict__ Y,
                                                      const float* __restrict__ x_cur,
                                                      const float* __restrict__ x_old,
                                                      const int* __restrict__ ent,
                                                      const int* __restrict__ row_start,
                                                      const int* __restrict__ deg2,
                                                      const float* __restrict__ dinv,
                                                      const float* __restrict__ K,
                                                      float* __restrict__ x_out) {
    __shared__ float Ks[64 * 65];   // K[c][o] at Ks[c*65+o]
    __shared__ float Ss[16][64];
    int t = threadIdx.x;
    for (int idx = t; idx < 4096; idx += 1024)
        Ks[(idx >> 6) * 65 + (idx & 63)] = K[idx];

    int wv = t >> 6, lane = t & 63;
    int n = blockIdx.x * 16 + wv;
    int c2  = lane & 31;        // channel-pair index (channels 2*c2, 2*c2+1)
    int sel = lane >> 5;        // 0: even entries, 1: odd entries
    float sx = 0.f, sy = 0.f;
    if (n < N_NODES) {
        const __half2 ynh = *(const __half2*)&Y[((size_t)n << 6) + 2 * c2];
        float ynx = __half2float(__low2half(ynh));
        float yny = __half2float(__high2half(ynh));
        float vn = dinv[n];
        int beg = __builtin_amdgcn_readfirstlane(row_start[n]);  // % 4 == 0
        int d   = __builtin_amdgcn_readfirstlane(deg2[n]);
        int end = beg + ((d + 3) & ~3);                          // padded, no tail
        for (int k = beg; k < end; k += 4) {
            int4 oo = *(const int4*)&ent[k];               // 16B-aligned, uniform
            int o0 = __builtin_amdgcn_readfirstlane(oo.x);
            int o1 = __builtin_amdgcn_readfirstlane(oo.y);
            int o2 = __builtin_amdgcn_readfirstlane(oo.z);
            int o3 = __builtin_amdgcn_readfirstlane(oo.w);
            int oa = sel ? o1 : o0;                        // pair 0: entries k,k+1
            int ob = sel ? o3 : o2;                        // pair 1: entries k+2,k+3
            const __half2 ha = *(const __half2*)&Y[((size_t)oa << 6) + 2 * c2];
            const __half2 hb = *(const __half2*)&Y[((size_t)ob << 6) + 2 * c2];
            float wa = dinv[oa] * vn;
            float wb = dinv[ob] * vn;
            float ax = __half2float(__low2half(ha)), ay = __half2float(__high2half(ha));
            float bx = __half2float(__low2half(hb)), by = __half2float(__high2half(hb));
            sx += wa * ftanh(wa * (ynx - ax));
            sy += wa * ftanh(wa * (yny - ay));
            sx += wb * ftanh(wb * (ynx - bx));
            sy += wb * ftanh(wb * (yny - by));
        }
    }
    // merge even/odd halves: partner lane is lane ^ 32
    sx += __shfl_xor(sx, 32, 64);
    sy += __shfl_xor(sy, 32, 64);
    if (lane < 32) {
        Ss[wv][2 * c2]     = sx;
        Ss[wv][2 * c2 + 1] = sy;
    }
    __syncthreads();
    if (n < N_NODES) {
        float acc = 0.f;
#pragma unroll 8
        for (int o = 0; o < 64; o++)
            acc += Ks[lane * 65 + o] * Ss[wv][o];   // 2-way bank alias (free) + broadcast
        float xc = x_cur[(size_t)n * 64 + lane];
        float xo = x_old[(size_t)n * 64 + lane];
        x_out[(size_t)n * 64 + lane] = 2.f * xc - xo - H2 * acc;
    }
}

// ---- out[n][o] = sum_c KNc[o][c] * x[n][c]; out is (N,40) f32 ----------
__global__ __launch_bounds__(256) void out_kernel(const float* __restrict__ x,
                                                  const float* __restrict__ Kc,
                                                  float* __restrict__ out) {
    __shared__ float xs[64 * 65];
    __shared__ float Ks[40 * 65];
    int t = threadIdx.x, n0 = blockIdx.x * 64;
    for (int idx = t; idx < 4096; idx += 256) {
        int r = idx >> 6, c = idx & 63;
        int gn = n0 + r;
        xs[r * 65 + c] = (gn < N_NODES) ? x[(size_t)gn * 64 + c] : 0.f;
    }
    for (int idx = t; idx < NUM_OUT * 64; idx += 256) {
        int r = idx >> 6, c = idx & 63;
        Ks[r * 65 + c] = Kc[idx];
    }
    __syncthreads();
    if (t < 160) {
        int tn = t & 15, to = t >> 4;
        float acc[4][4] = {};
        for (int c = 0; c < 64; c++) {
            float xv[4], kv[4];
#pragma unroll
            for (int i2 = 0; i2 < 4; i2++) xv[i2] = xs[(tn * 4 + i2) * 65 + c];
#pragma unroll
            for (int j = 0; j < 4; j++) kv[j] = Ks[(to * 4 + j) * 65 + c];
#pragma unroll
            for (int i2 = 0; i2 < 4; i2++)
#pragma unroll
                for (int j = 0; j < 4; j++) acc[i2][j] += xv[i2] * kv[j];
        }
#pragma unroll
        for (int i2 = 0; i2 < 4; i2++) {
            int node = n0 + tn * 4 + i2;
            if (node < N_NODES) {
#pragma unroll
                for (int j = 0; j < 4; j++)
                    out[(size_t)node * NUM_OUT + to * 4 + j] = acc[i2][j];
            }
        }
    }
}

extern "C" void kernel_launch(void* const* d_in, const int* in_sizes, int n_in,
                              void* d_out, int out_size, void* d_ws, size_t ws_size,
                              hipStream_t stream) {
    const float* xn = (const float*)d_in[0];
    const int*   I  = (const int*)d_in[1];
    const int*   J  = (const int*)d_in[2];
    const float* K1 = (const float*)d_in[4];
    const float* K2 = (const float*)d_in[5];
    const float* Kc = (const float*)d_in[6];

    const size_t NC = (size_t)N_NODES * NOPEN;  // 3.2M
    float*  f      = (float*)d_ws;
    float*  x_cur  = f;
    float*  x_old  = f + NC;
    __half* Y      = (__half*)(f + 2 * NC);     // 6.4 MB
    float*  dinv   = f + 2 * NC + NC / 2;
    int*    degi   = (int*)(dinv + N_NODES);
    int*    deg2   = degi + N_NODES;
    int*    row_st = deg2 + N_NODES;
    int*    cursor = row_st + N_NODES;
    int*    bsums  = cursor + N_NODES;
    int*    boff   = bsums + 256;
    int*    ent    = boff + 256;                // <= 2*E + 4*N ints = 13.6 MB

    dim3 B(256);
    const int GN = (N_NODES + 255) / 256;   // 196
    const int GE = (N_EDGES + 255) / 256;

    deg_init<<<GN, B, 0, stream>>>(degi, deg2);
    deg_count<<<GE, B, 0, stream>>>(I, J, degi, deg2);
    calc_dinv<<<GN, B, 0, stream>>>(degi, dinv);
    scan1<<<SCAN_BLOCKS, B, 0, stream>>>(deg2, row_st, bsums);
    scan2<<<1, B, 0, stream>>>(bsums, boff);
    scan3<<<SCAN_BLOCKS, B, 0, stream>>>(row_st, boff, cursor);
    pad_fill<<<GN, B, 0, stream>>>(row_st, deg2, ent);
    fill_ent<<<GE, B, 0, stream>>>(I, J, cursor, ent);

    const int NB = (N_NODES + 63) / 64;     // 782
    first_layer<<<NB, B, 0, stream>>>(xn, K1, x_cur, x_old);

    float* xc = x_cur;
    float* xo = x_old;
    for (int l = 0; l < NLAYER; l++) {
        mat_y<<<NB, B, 0, stream>>>(xc, K2 + l * NOPEN * NOPEN, Y);
        gather_update<<<(N_NODES + 15) / 16, dim3(1024), 0, stream>>>(
            Y, xc, xo, ent, row_st, deg2, dinv, K2 + l * NOPEN * NOPEN, xo);
        float* tmp = xc; xc = xo; xo = tmp;
    }
    out_kernel<<<NB, B, 0, stream>>>(xc, Kc, (float*)d_out);
}